// Round 1
// baseline (510.213 us; speedup 1.0000x reference)
//
#include <hip/hip_runtime.h>
#include <math.h>

// Problem constants (fixed by the reference)
constexpr int Bn = 16;    // batch
constexpr int Cn = 256;   // in channels
constexpr int Mn = 128;   // med channels
constexpr int Nn = 4096;  // H*W

// ---------------------------------------------------------------------------
// K1: o = w_o @ x + b_o ; v = w_v @ x + b_v   (per batch [M,C]x[C,N])
// block: 256 thr, tile m=128 (all) x n=32, K-chunks of 32. Shares x tile for
// both outputs. micro-tile 4m x 4n per array per thread.
// ---------------------------------------------------------------------------
__global__ __launch_bounds__(256) void k_proj(
    const float* __restrict__ x,
    const float* __restrict__ w_o, const float* __restrict__ b_o,
    const float* __restrict__ w_v, const float* __restrict__ b_v,
    float* __restrict__ o, float* __restrict__ v) {
  __shared__ float xs[32][32];       // [k][n]
  __shared__ float wos[32][132];     // [k][m] padded (132*4B=528=16B aligned rows)
  __shared__ float wvs[32][132];
  const int b = blockIdx.y;
  const int n_t = blockIdx.x * 32;
  const int t = threadIdx.x;
  const int m0 = (t >> 3) * 4;       // 0..124
  const int n0 = (t & 7) * 4;        // 0..28
  float acc_o[4][4] = {};
  float acc_v[4][4] = {};
  const float* xb = x + (size_t)b * Cn * Nn;

  for (int k0 = 0; k0 < Cn; k0 += 32) {
    { // x tile: 32k x 32n
      int kr = t >> 3;               // 0..31
      int nc = (t & 7) * 4;
      *(float4*)&xs[kr][nc] = *(const float4*)&xb[(size_t)(k0 + kr) * Nn + n_t + nc];
    }
    { // w tiles: 128m x 32k -> transposed [k][m]
      int k4 = (t & 7) * 4;
      int mr = t >> 3;               // 0..31
#pragma unroll
      for (int p = 0; p < 4; ++p) {
        int m = mr + p * 32;
        float4 a = *(const float4*)&w_o[(size_t)m * Cn + k0 + k4];
        float4 c = *(const float4*)&w_v[(size_t)m * Cn + k0 + k4];
        wos[k4 + 0][m] = a.x; wos[k4 + 1][m] = a.y; wos[k4 + 2][m] = a.z; wos[k4 + 3][m] = a.w;
        wvs[k4 + 0][m] = c.x; wvs[k4 + 1][m] = c.y; wvs[k4 + 2][m] = c.z; wvs[k4 + 3][m] = c.w;
      }
    }
    __syncthreads();
#pragma unroll
    for (int kk = 0; kk < 32; ++kk) {
      float4 a4 = *(const float4*)&wos[kk][m0];
      float4 c4 = *(const float4*)&wvs[kk][m0];
      float4 x4 = *(const float4*)&xs[kk][n0];
      float wa[4] = {a4.x, a4.y, a4.z, a4.w};
      float wc[4] = {c4.x, c4.y, c4.z, c4.w};
      float xx[4] = {x4.x, x4.y, x4.z, x4.w};
#pragma unroll
      for (int i = 0; i < 4; ++i)
#pragma unroll
        for (int j = 0; j < 4; ++j) {
          acc_o[i][j] = fmaf(wa[i], xx[j], acc_o[i][j]);
          acc_v[i][j] = fmaf(wc[i], xx[j], acc_v[i][j]);
        }
    }
    __syncthreads();
  }
#pragma unroll
  for (int i = 0; i < 4; ++i) {
    int m = m0 + i;
    float bo = b_o[m], bv = b_v[m];
    size_t base = ((size_t)(b * Mn + m)) * Nn + n_t + n0;
    float4 ov = {acc_o[i][0] + bo, acc_o[i][1] + bo, acc_o[i][2] + bo, acc_o[i][3] + bo};
    float4 vv = {acc_v[i][0] + bv, acc_v[i][1] + bv, acc_v[i][2] + bv, acc_v[i][3] + bv};
    *(float4*)&o[base] = ov;
    *(float4*)&v[base] = vv;
  }
}

// ---------------------------------------------------------------------------
// K2: row softmax stats over N for each (b,m): rm = max, rs = sum exp(v-rm)
// ---------------------------------------------------------------------------
__global__ __launch_bounds__(256) void k_rowstats(
    const float* __restrict__ v, float* __restrict__ rm, float* __restrict__ rs) {
  const int row = blockIdx.x;  // b*M + m
  const float* vr = v + (size_t)row * Nn;
  const int t = threadIdx.x;
  float vals[16];
  float mx = -1e30f;
#pragma unroll
  for (int p = 0; p < 4; ++p) {
    float4 v4 = *(const float4*)&vr[p * 1024 + t * 4];
    vals[p * 4 + 0] = v4.x; vals[p * 4 + 1] = v4.y;
    vals[p * 4 + 2] = v4.z; vals[p * 4 + 3] = v4.w;
    mx = fmaxf(mx, fmaxf(fmaxf(v4.x, v4.y), fmaxf(v4.z, v4.w)));
  }
  __shared__ float red[256];
  red[t] = mx;
  __syncthreads();
  for (int s = 128; s > 0; s >>= 1) {
    if (t < s) red[t] = fmaxf(red[t], red[t + s]);
    __syncthreads();
  }
  mx = red[0];
  __syncthreads();
  float sum = 0.f;
#pragma unroll
  for (int i = 0; i < 16; ++i) sum += expf(vals[i] - mx);
  red[t] = sum;
  __syncthreads();
  for (int s = 128; s > 0; s >>= 1) {
    if (t < s) red[t] += red[t + s];
    __syncthreads();
  }
  if (t == 0) { rm[row] = mx; rs[row] = red[0]; }
}

// ---------------------------------------------------------------------------
// K3: column softmax stats over M for each (b,n): cm, cs
// one thread per (b,n); column reads are coalesced across lanes (n fastest).
// ---------------------------------------------------------------------------
__global__ __launch_bounds__(256) void k_colstats(
    const float* __restrict__ v, float* __restrict__ cm, float* __restrict__ cs) {
  int idx = blockIdx.x * 256 + threadIdx.x;  // 0..B*N-1
  int b = idx >> 12;
  int n = idx & (Nn - 1);
  const float* vc = v + (size_t)b * Mn * Nn + n;
  float mx = -1e30f;
#pragma unroll 4
  for (int k = 0; k < Mn; ++k) mx = fmaxf(mx, vc[(size_t)k * Nn]);
  float sum = 0.f;
#pragma unroll 4
  for (int k = 0; k < Mn; ++k) sum += expf(vc[(size_t)k * Nn] - mx);
  cm[idx] = mx;
  cs[idx] = sum;
}

// ---------------------------------------------------------------------------
// K4: A[b,m,k] += sum_n [exp(v[m,n]-rm[m])/rs[m]] * [exp(v[k,n]-cm[n])/cs[n]]
// grid: (4 tile-pairs, 4 n-slices, B); block accumulates its n-slice locally
// then atomicAdds into A (A pre-zeroed by memset).
// ---------------------------------------------------------------------------
__global__ __launch_bounds__(256) void k_accA(
    const float* __restrict__ v,
    const float* __restrict__ rm, const float* __restrict__ rs,
    const float* __restrict__ cm, const float* __restrict__ cs,
    float* __restrict__ A) {
  __shared__ float evT[32][68];  // [j][m-local]
  __shared__ float esT[32][68];  // [j][k-local]
  const int b = blockIdx.z;
  const int mt = blockIdx.x & 1, kt = blockIdx.x >> 1;
  const int m0 = mt * 64, k0 = kt * 64;
  const int ns = blockIdx.y;
  const int t = threadIdx.x;
  const int tm = (t >> 4) * 4, tk = (t & 15) * 4;
  const int j = t & 31, i0 = t >> 5;
  float acc[4][4] = {};
  const float* vb = v + (size_t)b * Mn * Nn;
  const float* rmb = rm + b * Mn;
  const float* rsb = rs + b * Mn;
  const float* cmb = cm + b * Nn;
  const float* csb = cs + b * Nn;

  float rmv[8], irs[8];
#pragma unroll
  for (int p = 0; p < 8; ++p) {
    int i = i0 + p * 8;
    rmv[p] = rmb[m0 + i];
    irs[p] = 1.0f / rsb[m0 + i];
  }

  for (int nc = ns * 1024; nc < ns * 1024 + 1024; nc += 32) {
    float cmj = cmb[nc + j];
    float icj = 1.0f / csb[nc + j];
#pragma unroll
    for (int p = 0; p < 8; ++p) {
      int i = i0 + p * 8;
      float vm = vb[(size_t)(m0 + i) * Nn + nc + j];
      evT[j][i] = expf(vm - rmv[p]) * irs[p];
      float vk = vb[(size_t)(k0 + i) * Nn + nc + j];
      esT[j][i] = expf(vk - cmj) * icj;
    }
    __syncthreads();
#pragma unroll
    for (int jj = 0; jj < 32; ++jj) {
      float4 e4 = *(const float4*)&evT[jj][tm];
      float4 s4 = *(const float4*)&esT[jj][tk];
      float e[4] = {e4.x, e4.y, e4.z, e4.w};
      float s[4] = {s4.x, s4.y, s4.z, s4.w};
#pragma unroll
      for (int a = 0; a < 4; ++a)
#pragma unroll
        for (int c2 = 0; c2 < 4; ++c2) acc[a][c2] = fmaf(e[a], s[c2], acc[a][c2]);
    }
    __syncthreads();
  }
#pragma unroll
  for (int a = 0; a < 4; ++a)
#pragma unroll
    for (int c2 = 0; c2 < 4; ++c2)
      atomicAdd(&A[((size_t)(b * Mn + m0 + tm + a)) * Mn + k0 + tk + c2], acc[a][c2]);
}

// ---------------------------------------------------------------------------
// K5: W2[b,c,m] = sum_k w_c[c,k] * A[b,m,k]   ([256x128]x[128x128]^T per b)
// grid: (m-tile 2, c-tile 4, B), tile 64x64, K=128 in two 64-chunks via LDS.
// ---------------------------------------------------------------------------
__global__ __launch_bounds__(256) void k_w2(
    const float* __restrict__ w_c, const float* __restrict__ A, float* __restrict__ W2) {
  __shared__ float As[64][68];   // [k][m-local]
  __shared__ float wcs[64][68];  // [k][c-local]
  const int b = blockIdx.z;
  const int m0 = blockIdx.x * 64;
  const int c0 = blockIdx.y * 64;
  const int t = threadIdx.x;
  const int tc = (t >> 4) * 4, tmm = (t & 15) * 4;
  float acc[4][4] = {};
  for (int k0 = 0; k0 < Mn; k0 += 64) {
    int r = t >> 2;             // 0..63
    int k4 = (t & 3) * 4;
#pragma unroll
    for (int p = 0; p < 4; ++p) {
      int k = k4 + p * 16;
      float4 a4 = *(const float4*)&A[((size_t)(b * Mn + m0 + r)) * Mn + k0 + k];
      As[k + 0][r] = a4.x; As[k + 1][r] = a4.y; As[k + 2][r] = a4.z; As[k + 3][r] = a4.w;
      float4 w4 = *(const float4*)&w_c[(size_t)(c0 + r) * Mn + k0 + k];
      wcs[k + 0][r] = w4.x; wcs[k + 1][r] = w4.y; wcs[k + 2][r] = w4.z; wcs[k + 3][r] = w4.w;
    }
    __syncthreads();
#pragma unroll
    for (int kk = 0; kk < 64; ++kk) {
      float4 w4 = *(const float4*)&wcs[kk][tc];
      float4 a4 = *(const float4*)&As[kk][tmm];
      float w[4] = {w4.x, w4.y, w4.z, w4.w};
      float a[4] = {a4.x, a4.y, a4.z, a4.w};
#pragma unroll
      for (int i = 0; i < 4; ++i)
#pragma unroll
        for (int jj = 0; jj < 4; ++jj) acc[i][jj] = fmaf(w[i], a[jj], acc[i][jj]);
    }
    __syncthreads();
  }
#pragma unroll
  for (int i = 0; i < 4; ++i) {
    size_t base = ((size_t)(b * Cn + c0 + tc + i)) * Mn + m0 + tmm;
    float4 r4 = {acc[i][0], acc[i][1], acc[i][2], acc[i][3]};
    *(float4*)&W2[base] = r4;
  }
}

// ---------------------------------------------------------------------------
// K6: out[b,c,n] = gamma*relu(sum_m W2[b,c,m]*o[b,m,n] + b_c[c]) + x[b,c,n]
// grid: (n-tile 32, c-tile 4, B); tile 64c x 128n, K=128 in 32-chunks.
// micro: 4c x (4n + 4n at +64) per thread.
// ---------------------------------------------------------------------------
__global__ __launch_bounds__(256) void k_final(
    const float* __restrict__ W2, const float* __restrict__ o,
    const float* __restrict__ x, const float* __restrict__ b_c,
    const float* __restrict__ gamma, float* __restrict__ out) {
  __shared__ float os[32][128];  // [k][n]
  __shared__ float w2T[32][68];  // [k][c-local]
  const int b = blockIdx.z;
  const int c_t = blockIdx.y * 64;
  const int n_t = blockIdx.x * 128;
  const int t = threadIdx.x;
  const int tc = (t >> 4) * 4;       // 0..60
  const int tn = (t & 15) * 4;       // 0..60 (+64 for second half)
  float acc[4][8] = {};
  const float* ob = o + (size_t)b * Mn * Nn;
  const float* W2b = W2 + ((size_t)b * Cn + c_t) * Mn;

  for (int k0 = 0; k0 < Mn; k0 += 32) {
    { // o tile 32k x 128n
      int kr = t >> 5, nc = (t & 31) * 4;
#pragma unroll
      for (int p = 0; p < 4; ++p)
        *(float4*)&os[kr + p * 8][nc] =
            *(const float4*)&ob[(size_t)(k0 + kr + p * 8) * Nn + n_t + nc];
    }
    { // W2 tile 64c x 32k -> [k][c]
      int cc = t >> 2, k4 = (t & 3) * 4;
#pragma unroll
      for (int p = 0; p < 2; ++p) {
        int k = k4 + p * 16;
        float4 w4 = *(const float4*)&W2b[(size_t)cc * Mn + k0 + k];
        w2T[k + 0][cc] = w4.x; w2T[k + 1][cc] = w4.y;
        w2T[k + 2][cc] = w4.z; w2T[k + 3][cc] = w4.w;
      }
    }
    __syncthreads();
#pragma unroll
    for (int kk = 0; kk < 32; ++kk) {
      float4 w4 = *(const float4*)&w2T[kk][tc];
      float4 oa = *(const float4*)&os[kk][tn];
      float4 obb = *(const float4*)&os[kk][tn + 64];
      float w[4] = {w4.x, w4.y, w4.z, w4.w};
      float oo[8] = {oa.x, oa.y, oa.z, oa.w, obb.x, obb.y, obb.z, obb.w};
#pragma unroll
      for (int i = 0; i < 4; ++i)
#pragma unroll
        for (int jj = 0; jj < 8; ++jj) acc[i][jj] = fmaf(w[i], oo[jj], acc[i][jj]);
    }
    __syncthreads();
  }
  float g = gamma[0];
#pragma unroll
  for (int i = 0; i < 4; ++i) {
    int c = c_t + tc + i;
    float bias = b_c[c];
    size_t base = ((size_t)(b * Cn + c)) * Nn + n_t + tn;
#pragma unroll
    for (int h = 0; h < 2; ++h) {
      size_t idx = base + h * 64;
      float4 x4 = *(const float4*)&x[idx];
      float4 r;
      r.x = g * fmaxf(acc[i][h * 4 + 0] + bias, 0.f) + x4.x;
      r.y = g * fmaxf(acc[i][h * 4 + 1] + bias, 0.f) + x4.y;
      r.z = g * fmaxf(acc[i][h * 4 + 2] + bias, 0.f) + x4.z;
      r.w = g * fmaxf(acc[i][h * 4 + 3] + bias, 0.f) + x4.w;
      *(float4*)&out[idx] = r;
    }
  }
}

// ---------------------------------------------------------------------------
extern "C" void kernel_launch(void* const* d_in, const int* in_sizes, int n_in,
                              void* d_out, int out_size, void* d_ws, size_t ws_size,
                              hipStream_t stream) {
  const float* x   = (const float*)d_in[0];
  const float* w_o = (const float*)d_in[1];
  const float* b_o = (const float*)d_in[2];
  const float* w_v = (const float*)d_in[3];
  const float* b_v = (const float*)d_in[4];
  const float* w_c = (const float*)d_in[5];
  const float* b_c = (const float*)d_in[6];
  const float* gm  = (const float*)d_in[7];

  float* ws = (float*)d_ws;
  float* o  = ws;                               // B*M*N
  float* v  = o  + (size_t)Bn * Mn * Nn;        // B*M*N
  float* rm = v  + (size_t)Bn * Mn * Nn;        // B*M
  float* rs = rm + Bn * Mn;                     // B*M
  float* cm = rs + Bn * Mn;                     // B*N
  float* cs = cm + Bn * Nn;                     // B*N
  float* A  = cs + Bn * Nn;                     // B*M*M
  float* W2 = A  + (size_t)Bn * Mn * Mn;        // B*C*M

  k_proj<<<dim3(Nn / 32, Bn), 256, 0, stream>>>(x, w_o, b_o, w_v, b_v, o, v);
  k_rowstats<<<dim3(Bn * Mn), 256, 0, stream>>>(v, rm, rs);
  k_colstats<<<dim3(Bn * Nn / 256), 256, 0, stream>>>(v, cm, cs);
  hipMemsetAsync(A, 0, (size_t)Bn * Mn * Mn * sizeof(float), stream);
  k_accA<<<dim3(4, 4, Bn), 256, 0, stream>>>(v, rm, rs, cm, cs, A);
  k_w2<<<dim3(Mn / 64, Cn / 64, Bn), 256, 0, stream>>>(w_c, A, W2);
  k_final<<<dim3(Nn / 128, Cn / 64, Bn), 256, 0, stream>>>(W2, o, x, b_c, gm, (float*)d_out);
}